// Round 19
// baseline (766.145 us; speedup 1.0000x reference)
//
#include <hip/hip_runtime.h>
#include <cstdint>
#include <cstddef>

// Problem constants (from reference setup_inputs)
#define N_NODES  50000
#define N_EDGES  800000
#define DIM_IN   128
#define DIM_H    512
#define N_GRAPHS 64
#define DIM_OUT  10
#define BN_EPS   1e-5f
#define SCAN_B   196   // ceil(N_NODES / 256)

typedef _Float16 h16;
using f16x8 = __attribute__((ext_vector_type(8))) _Float16;
using f32x4 = __attribute__((ext_vector_type(4))) float;

__device__ inline float4 add4(float4 a, float4 b) {
    return make_float4(a.x + b.x, a.y + b.y, a.z + b.z, a.w + b.w);
}

// ---------------------------------------------------------------------------
// Weight cast+transpose (all 4 weights) + deg zeroing, one launch.
// ---------------------------------------------------------------------------
__global__ __launch_bounds__(256) void k_wcast_all(
    const float* __restrict__ W1a, const float* __restrict__ W1b,
    const float* __restrict__ W2a, const float* __restrict__ W2b,
    h16* __restrict__ Wt1a, h16* __restrict__ Wt1b,
    h16* __restrict__ Wt2a, h16* __restrict__ Wt2b,
    int* __restrict__ deg)
{
    // zero deg[] grid-stride (416*256 threads)
    for (int i = blockIdx.x * 256 + threadIdx.x; i < N_NODES; i += 416 * 256)
        deg[i] = 0;

    int b = blockIdx.x;
    const float* W; h16* Wt; int K, base;
    if (b < 32)       { W = W1a; Wt = Wt1a; K = DIM_IN; base = 0; }
    else if (b < 160) { W = W1b; Wt = Wt1b; K = DIM_H;  base = 32; }
    else if (b < 288) { W = W2a; Wt = Wt2a; K = DIM_H;  base = 160; }
    else              { W = W2b; Wt = Wt2b; K = DIM_H;  base = 288; }
    int t = (b - base) * 256 + threadIdx.x;
    int total = (K >> 3) * DIM_H;
    if (t >= total) return;
    int k8 = t / DIM_H;
    int n  = t - k8 * DIM_H;
    f16x8 o;
#pragma unroll
    for (int j = 0; j < 8; ++j)
        o[j] = (h16)W[(size_t)(k8 * 8 + j) * DIM_H + n];
    *reinterpret_cast<f16x8*>(&Wt[(size_t)n * K + k8 * 8]) = o;
}

// ---------------------------------------------------------------------------
// CSR build: counting sort of edges by dst.  Hierarchical 3-phase scan.
// ---------------------------------------------------------------------------
__global__ __launch_bounds__(256) void k_deg(
    const int* __restrict__ dst, int* __restrict__ deg)
{
    int t = blockIdx.x * 256 + threadIdx.x;
    if (t < N_EDGES) atomicAdd(&deg[dst[t]], 1);
}

__global__ __launch_bounds__(256) void k_scan1(
    const int* __restrict__ deg, int* __restrict__ bsum)
{
    __shared__ int s[256];
    int tid = threadIdx.x;
    int i = blockIdx.x * 256 + tid;
    s[tid] = (i < N_NODES) ? deg[i] : 0;
    __syncthreads();
    for (int off = 128; off > 0; off >>= 1) {
        if (tid < off) s[tid] += s[tid + off];
        __syncthreads();
    }
    if (tid == 0) bsum[blockIdx.x] = s[0];
}

__global__ __launch_bounds__(256) void k_scan2(
    const int* __restrict__ bsum, int* __restrict__ boff)
{
    __shared__ int s[256];
    int tid = threadIdx.x;
    s[tid] = (tid < SCAN_B) ? bsum[tid] : 0;
    __syncthreads();
    for (int off = 1; off < 256; off <<= 1) {
        int u = (tid >= off) ? s[tid - off] : 0;
        __syncthreads();
        s[tid] += u;
        __syncthreads();
    }
    if (tid < SCAN_B) boff[tid] = (tid == 0) ? 0 : s[tid - 1];
}

// phase 3 + csum/csq zeroing (block 0)
__global__ __launch_bounds__(256) void k_scan3(
    const int* __restrict__ deg, const int* __restrict__ boff,
    int* __restrict__ rowptr, int* __restrict__ cursor,
    float* __restrict__ csum)
{
    __shared__ int s[256];
    int tid = threadIdx.x;
    int i = blockIdx.x * 256 + tid;
    int v = (i < N_NODES) ? deg[i] : 0;
    s[tid] = v;
    __syncthreads();
    for (int off = 1; off < 256; off <<= 1) {
        int u = (tid >= off) ? s[tid - off] : 0;
        __syncthreads();
        s[tid] += u;
        __syncthreads();
    }
    int excl = s[tid] - v + boff[blockIdx.x];
    if (i < N_NODES) {
        rowptr[i] = excl;
        cursor[i] = excl;
        if (i == N_NODES - 1) rowptr[N_NODES] = excl + v;   // == N_EDGES
    }
    if (blockIdx.x == 0)
        for (int z = tid; z < 2 * DIM_H; z += 256) csum[z] = 0.f;  // csum+csq
}

__global__ __launch_bounds__(256) void k_fill(
    const int* __restrict__ src, const int* __restrict__ dst,
    int* __restrict__ cursor, int* __restrict__ eidx)
{
    int t = blockIdx.x * 256 + threadIdx.x;
    if (t >= N_EDGES) return;
    int pos = atomicAdd(&cursor[dst[t]], 1);
    eidx[pos] = src[t];
}

// ---------------------------------------------------------------------------
// Gather aggregation: out[v] = X[v] + sum_{u in N_in(v)} X[u]
// ---------------------------------------------------------------------------
__global__ __launch_bounds__(256) void k_gather128(
    const float4* __restrict__ X, const int* __restrict__ rowptr,
    const int* __restrict__ eidx, f16x8* __restrict__ out)
{
    int t = blockIdx.x * 256 + threadIdx.x;
    int v = t >> 4, lane = t & 15;
    if (v >= N_NODES) return;
    int r0 = rowptr[v], r1 = rowptr[v + 1];
    float4 a0 = X[(size_t)v * 32 + lane * 2];
    float4 a1 = X[(size_t)v * 32 + lane * 2 + 1];
    for (int j = r0; j < r1; ++j) {
        int s = eidx[j];
        a0 = add4(a0, X[(size_t)s * 32 + lane * 2]);
        a1 = add4(a1, X[(size_t)s * 32 + lane * 2 + 1]);
    }
    f16x8 o;
    o[0] = (h16)a0.x; o[1] = (h16)a0.y; o[2] = (h16)a0.z; o[3] = (h16)a0.w;
    o[4] = (h16)a1.x; o[5] = (h16)a1.y; o[6] = (h16)a1.z; o[7] = (h16)a1.w;
    out[(size_t)v * 16 + lane] = o;
}

// 512-dim gather + csum/csq re-zero (block 0, for layer-2 stats GEMM).
__global__ __launch_bounds__(256) void k_gather512h(
    const f16x8* __restrict__ X, const int* __restrict__ rowptr,
    const int* __restrict__ eidx, f16x8* __restrict__ out,
    float* __restrict__ csum)
{
    if (blockIdx.x == 0)
        for (int z = threadIdx.x; z < 2 * DIM_H; z += 256) csum[z] = 0.f;

    int t = blockIdx.x * 256 + threadIdx.x;
    int v = t >> 6, lane = t & 63;
    if (v >= N_NODES) return;
    int r0 = rowptr[v], r1 = rowptr[v + 1];
    f16x8 sv = X[(size_t)v * 64 + lane];
    float a[8];
#pragma unroll
    for (int i = 0; i < 8; ++i) a[i] = (float)sv[i];
    int j = r0;
    for (; j + 7 < r1; j += 8) {
        f16x8 b0 = X[(size_t)eidx[j]     * 64 + lane];
        f16x8 b1 = X[(size_t)eidx[j + 1] * 64 + lane];
        f16x8 b2 = X[(size_t)eidx[j + 2] * 64 + lane];
        f16x8 b3 = X[(size_t)eidx[j + 3] * 64 + lane];
        f16x8 b4 = X[(size_t)eidx[j + 4] * 64 + lane];
        f16x8 b5 = X[(size_t)eidx[j + 5] * 64 + lane];
        f16x8 b6 = X[(size_t)eidx[j + 6] * 64 + lane];
        f16x8 b7 = X[(size_t)eidx[j + 7] * 64 + lane];
#pragma unroll
        for (int i = 0; i < 8; ++i)
            a[i] += (((float)b0[i] + (float)b1[i]) + ((float)b2[i] + (float)b3[i]))
                  + (((float)b4[i] + (float)b5[i]) + ((float)b6[i] + (float)b7[i]));
    }
    for (; j + 1 < r1; j += 2) {
        f16x8 b0 = X[(size_t)eidx[j]     * 64 + lane];
        f16x8 b1 = X[(size_t)eidx[j + 1] * 64 + lane];
#pragma unroll
        for (int i = 0; i < 8; ++i) a[i] += (float)b0[i] + (float)b1[i];
    }
    if (j < r1) {
        f16x8 b = X[(size_t)eidx[j] * 64 + lane];
#pragma unroll
        for (int i = 0; i < 8; ++i) a[i] += (float)b[i];
    }
    f16x8 o;
#pragma unroll
    for (int i = 0; i < 8; ++i) o[i] = (h16)a[i];
    out[(size_t)v * 64 + lane] = o;
}

// ---------------------------------------------------------------------------
// MFMA GEMM (fp16 A + fp16 k-major B, fp32 accum, fp16 C):
//   C[M,N] = op(A) @ B + bias
//   AFFINE: in-block BN fold (sf=g*rsqrt(var+eps), cf=be-mu*sf from
//           csum/csq/gam/bet -> LDS), then a -> relu(a*sf[k]+cf[k]) on load.
//   RELU: epilogue relu;  STATS: fused column sum/sum-sq (pre-ReLU)
// BM=128, BN=256, BK=32, single-buffer 24(+4)KB LDS, 2 barriers/K-step,
// register-staged with next-tile prefetch overlapping MFMA (R15 structure,
// best measured of R15/R16/R17/R18 family).
// LDS flat-swizzled (T2): entry(row,kb) at [row*4 + (kb ^ (row&3))]
// -> conflict-free stores, 2-way (free) reads [R14: conflicts ~0].
// 512 threads = 8 waves (2x4), wave tile 64x64, 4x4 frags of 16x16x32.
// Fragment maps (gfx950, learn_hip m89-verified family):
//   A: lane l holds A[l&15][8*(l>>4)+j] ; B: lane l holds B[8*(l>>4)+j][l&15]
//   D: lane l reg r holds D[4*(l>>4)+r][l&15]
// ---------------------------------------------------------------------------
template<bool AFFINE, bool RELU, bool STATS>
__global__ __launch_bounds__(512) void k_gemm_mfma(
    const h16* __restrict__ A, const h16* __restrict__ Bt,
    const float* __restrict__ bias,
    float* __restrict__ csum, float* __restrict__ csq,
    const float* __restrict__ gam, const float* __restrict__ bet,
    h16* __restrict__ C, int M, int N, int K, int lda)
{
    __shared__ f16x8 As[128 * 4];   //  8 KB, swizzled
    __shared__ f16x8 Bs[256 * 4];   // 16 KB
    __shared__ float sfl[DIM_H], cfl[DIM_H];   // 4 KB (AFFINE only)

    const int tid  = threadIdx.x;
    const int lane = tid & 63;
    const int w    = tid >> 6;          // 0..7
    const int wr   = w >> 2;            // 0..1 (row half)
    const int wc   = w & 3;             // 0..3 (col quarter)
    const int l15  = lane & 15;
    const int lk   = lane >> 4;         // k-group 0..3
    const int m0   = blockIdx.x * 128;
    const int n0   = blockIdx.y * 256;

    if (AFFINE) {
        const float invM = 1.0f / (float)N_NODES;
        for (int cc = tid; cc < K; cc += 512) {
            float mu  = csum[cc] * invM;
            float var = csq[cc] * invM - mu * mu;
            float s   = gam[cc] * rsqrtf(var + BN_EPS);
            sfl[cc] = s;
            cfl[cc] = bet[cc] - mu * s;
        }
        __syncthreads();
    }

    // A staging: 1 chunk/thread: row a_row = tid>>2, kb = tid&3
    const int a_row = tid >> 2;         // 0..127
    const int kb    = tid & 3;          // 0..3
    const int aswz  = kb ^ (a_row & 3);
    int ar = m0 + a_row; if (ar >= M) ar = M - 1;     // clamp; stores predicated
    const h16* aptr = A + (size_t)ar * lda + kb * 8;
    // B staging: 2 chunks/thread: cols b_col, b_col+128, same kb
    const int b_col = tid >> 2;         // 0..127  (+128 preserves &3)
    const int bswz  = kb ^ (b_col & 3);
    const h16* bptr = Bt + (size_t)(n0 + b_col) * K + kb * 8;
    const size_t bstride = (size_t)128 * K;   // +128 cols

    f32x4 acc[4][4];
#pragma unroll
    for (int m = 0; m < 4; ++m)
#pragma unroll
        for (int n = 0; n < 4; ++n)
            acc[m][n] = (f32x4){0.f, 0.f, 0.f, 0.f};

    f16x8 av, bw0, bw1;

    auto load_tile = [&](int k0) {
        av  = *reinterpret_cast<const f16x8*>(aptr + k0);
        if (AFFINE) {
            int kk = k0 + kb * 8;
            float4 s0 = *reinterpret_cast<const float4*>(&sfl[kk]);
            float4 s1 = *reinterpret_cast<const float4*>(&sfl[kk + 4]);
            float4 c0 = *reinterpret_cast<const float4*>(&cfl[kk]);
            float4 c1 = *reinterpret_cast<const float4*>(&cfl[kk + 4]);
            float sarr[8] = {s0.x, s0.y, s0.z, s0.w, s1.x, s1.y, s1.z, s1.w};
            float carr[8] = {c0.x, c0.y, c0.z, c0.w, c1.x, c1.y, c1.z, c1.w};
#pragma unroll
            for (int i = 0; i < 8; ++i)
                av[i] = (h16)fmaxf(fmaf((float)av[i], sarr[i], carr[i]), 0.f);
        }
        bw0 = *reinterpret_cast<const f16x8*>(bptr + k0);
        bw1 = *reinterpret_cast<const f16x8*>(bptr + bstride + k0);
    };

    load_tile(0);

    for (int k0 = 0; k0 < K; k0 += 32) {
        __syncthreads();   // previous tile fully consumed
        As[a_row * 4 + aswz]          = av;
        Bs[b_col * 4 + bswz]          = bw0;
        Bs[(b_col + 128) * 4 + bswz]  = bw1;
        __syncthreads();   // tile ready

        if (k0 + 32 < K) load_tile(k0 + 32);   // prefetch overlaps MFMA below

        f16x8 af[4], bf[4];
#pragma unroll
        for (int m = 0; m < 4; ++m) {
            int row = wr * 64 + m * 16 + l15;
            af[m] = As[row * 4 + (lk ^ (row & 3))];
        }
#pragma unroll
        for (int n = 0; n < 4; ++n) {
            int col = wc * 64 + n * 16 + l15;
            bf[n] = Bs[col * 4 + (lk ^ (col & 3))];
        }
#pragma unroll
        for (int m = 0; m < 4; ++m)
#pragma unroll
            for (int n = 0; n < 4; ++n)
                acc[m][n] = __builtin_amdgcn_mfma_f32_16x16x32_f16(
                    af[m], bf[n], acc[m][n], 0, 0, 0);
    }

    // ---- epilogue (fp16 store + optional fused column stats) ----
#pragma unroll
    for (int n = 0; n < 4; ++n) {
        int col = n0 + wc * 64 + n * 16 + l15;
        float bb = bias[col];
        float sp = 0.f, qp = 0.f;
#pragma unroll
        for (int m = 0; m < 4; ++m) {
            int row0 = m0 + wr * 64 + m * 16 + lk * 4;
#pragma unroll
            for (int r = 0; r < 4; ++r) {
                int row = row0 + r;
                if (row < M) {
                    float v = acc[m][n][r] + bb;
                    if (STATS) { sp += v; qp += v * v; }
                    if (RELU) v = fmaxf(v, 0.f);
                    C[(size_t)row * N + col] = (h16)v;
                }
            }
        }
        if (STATS) {
            sp += __shfl_xor(sp, 16); qp += __shfl_xor(qp, 16);
            sp += __shfl_xor(sp, 32); qp += __shfl_xor(qp, 32);
            if (lk == 0) {
                atomicAdd(&csum[col], sp);
                atomicAdd(&csq[col], qp);
            }
        }
    }
}

// ---------------------------------------------------------------------------
// Fused pool + 2-layer head: one block per graph (batch sorted).
//   pooled[c] = sum_{v in graph} H[v][c]  (binary-search bounds, no atomics)
//   q = relu(pooled @ Wl1 + bl1);  out = q @ Wl2 + bl2
// ---------------------------------------------------------------------------
__global__ __launch_bounds__(512) void k_poolhead(
    const h16* __restrict__ H, const int* __restrict__ batch,
    const float* __restrict__ Wl1, const float* __restrict__ bl1,
    const float* __restrict__ Wl2, const float* __restrict__ bl2,
    float* __restrict__ out)
{
    __shared__ float rowp[DIM_H];
    __shared__ float qv[DIM_H];
    __shared__ int bounds[2];
    int g = blockIdx.x, c = threadIdx.x;
    if (c < 2) {
        int target = g + c;           // lower_bound(batch, target)
        int lo = 0, hi = N_NODES;
        while (lo < hi) {
            int mid = (lo + hi) >> 1;
            if (batch[mid] < target) lo = mid + 1; else hi = mid;
        }
        bounds[c] = lo;
    }
    __syncthreads();
    int r0 = bounds[0], r1 = bounds[1];
    float s = 0.f;
    for (int r = r0; r < r1; ++r)
        s += (float)H[(size_t)r * DIM_H + c];
    rowp[c] = s;
    __syncthreads();
    float acc = 0.f;
    for (int k = 0; k < DIM_H; ++k)
        acc = fmaf(rowp[k], Wl1[(size_t)k * DIM_H + c], acc);
    qv[c] = fmaxf(acc + bl1[c], 0.f);
    __syncthreads();
    if (c < DIM_OUT) {
        float a2 = 0.f;
        for (int k = 0; k < DIM_H; ++k)
            a2 = fmaf(qv[k], Wl2[(size_t)k * DIM_OUT + c], a2);
        out[g * DIM_OUT + c] = a2 + bl2[c];
    }
}

// ---------------------------------------------------------------------------
extern "C" void kernel_launch(void* const* d_in, const int* in_sizes, int n_in,
                              void* d_out, int out_size, void* d_ws, size_t ws_size,
                              hipStream_t stream)
{
    const float* x   = (const float*)d_in[0];
    const int*   ei  = (const int*)d_in[1];
    const int*   src = ei;
    const int*   dst = ei + N_EDGES;
    const int*   batch = (const int*)d_in[2];
    const float* W1a = (const float*)d_in[3];
    const float* b1a = (const float*)d_in[4];
    const float* g1  = (const float*)d_in[5];
    const float* be1 = (const float*)d_in[6];
    const float* W1b = (const float*)d_in[7];
    const float* b1b = (const float*)d_in[8];
    const float* W2a = (const float*)d_in[9];
    const float* b2a = (const float*)d_in[10];
    const float* g2  = (const float*)d_in[11];
    const float* be2 = (const float*)d_in[12];
    const float* W2b = (const float*)d_in[13];
    const float* b2b = (const float*)d_in[14];
    const float* Wl1 = (const float*)d_in[15];
    const float* bl1 = (const float*)d_in[16];
    const float* Wl2 = (const float*)d_in[17];
    const float* bl2 = (const float*)d_in[18];

    char* ws = (char*)d_ws;
    const size_t ROW_H = (size_t)N_NODES * DIM_H * 2;   // 51,200,000

    if (ws_size < 110000000ull) {
        hipMemsetAsync(d_out, 0, (size_t)out_size * 4, stream);
        return;
    }
    h16* B1h = (h16*)(ws + 0);
    h16* B2h = (h16*)(ws + ROW_H);
    h16* XAh = B2h;                                   // 12.8 MB, dead after GEMM1
    char* cp  = ws + 2 * ROW_H;                       // 102,400,000
    int* deg    = (int*)(cp + 0);
    int* rowptr = (int*)(cp + 200192);
    int* cursor = (int*)(cp + 400384);
    int* eidx   = (int*)(cp + 600576);
    char* sm    = cp + 3800576;
    float* csum   = (float*)(sm + 0);                 // [512]
    float* csq    = (float*)(sm + 2048);              // [512], contiguous after csum
    char* wt = sm + 8192;
    h16* Wt1a = (h16*)(wt);                           // [512][128] 128 KB
    h16* Wt1b = (h16*)(wt + 131072);                  // [512][512] 512 KB
    h16* Wt2a = (h16*)(wt + 131072 + 524288);
    h16* Wt2b = (h16*)(wt + 131072 + 2 * 524288);
    int* bsum = (int*)(wt + 131072 + 3 * 524288);     // [196]
    int* boff = bsum + 256;                           // [196]

    const dim3 gemm_grid(391, 2);   // ceil(50000/128) x 512/256
    const int EB = (N_EDGES + 255) / 256;

    // 1) weight cast+transpose + deg zero
    k_wcast_all<<<416, 256, 0, stream>>>(W1a, W1b, W2a, W2b,
                                         Wt1a, Wt1b, Wt2a, Wt2b, deg);
    // 2-6) CSR build (scan3 zeroes csum/csq for layer-1 stats)
    k_deg<<<EB, 256, 0, stream>>>(dst, deg);
    k_scan1<<<SCAN_B, 256, 0, stream>>>(deg, bsum);
    k_scan2<<<1, 256, 0, stream>>>(bsum, boff);
    k_scan3<<<SCAN_B, 256, 0, stream>>>(deg, boff, rowptr, cursor, csum);
    k_fill<<<EB, 256, 0, stream>>>(src, dst, cursor, eidx);

    // 7-9) layer 1
    k_gather128<<<(N_NODES * 16 + 255) / 256, 256, 0, stream>>>(
        (const float4*)x, rowptr, eidx, (f16x8*)XAh);
    k_gemm_mfma<false, false, true><<<gemm_grid, 512, 0, stream>>>(
        XAh, Wt1a, b1a, csum, csq, nullptr, nullptr, B1h,
        N_NODES, DIM_H, DIM_IN, DIM_IN);
    k_gemm_mfma<true, true, false><<<gemm_grid, 512, 0, stream>>>(
        B1h, Wt1b, b1b, csum, csq, g1, be1, B2h,
        N_NODES, DIM_H, DIM_H, DIM_H);

    // 10-12) layer 2 (gather re-zeroes csum/csq for layer-2 stats)
    k_gather512h<<<(N_NODES * 64) / 256, 256, 0, stream>>>(
        (const f16x8*)B2h, rowptr, eidx, (f16x8*)B1h, csum);
    k_gemm_mfma<false, false, true><<<gemm_grid, 512, 0, stream>>>(
        B1h, Wt2a, b2a, csum, csq, nullptr, nullptr, B2h,
        N_NODES, DIM_H, DIM_H, DIM_H);
    k_gemm_mfma<true, true, false><<<gemm_grid, 512, 0, stream>>>(
        B2h, Wt2b, b2b, csum, csq, g2, be2, B1h,
        N_NODES, DIM_H, DIM_H, DIM_H);

    // 13) fused pool + head
    k_poolhead<<<N_GRAPHS, 512, 0, stream>>>(
        B1h, batch, Wl1, bl1, Wl2, bl2, (float*)d_out);
}

// Round 21
// 598.763 us; speedup vs baseline: 1.2795x; 1.2795x over previous
//
#include <hip/hip_runtime.h>
#include <cstdint>
#include <cstddef>

// Problem constants (from reference setup_inputs)
#define N_NODES  50000
#define N_EDGES  800000
#define DIM_IN   128
#define DIM_H    512
#define N_GRAPHS 64
#define DIM_OUT  10
#define BN_EPS   1e-5f
#define SCAN_B   196   // ceil(N_NODES / 256)

typedef _Float16 h16;
using f16x8 = __attribute__((ext_vector_type(8))) _Float16;
using f32x4 = __attribute__((ext_vector_type(4))) float;

__device__ inline float4 add4(float4 a, float4 b) {
    return make_float4(a.x + b.x, a.y + b.y, a.z + b.z, a.w + b.w);
}

// ---------------------------------------------------------------------------
// Weight cast+transpose (all 4 weights) + deg/pooled zeroing, one launch.
// ---------------------------------------------------------------------------
__global__ __launch_bounds__(256) void k_wcast_all(
    const float* __restrict__ W1a, const float* __restrict__ W1b,
    const float* __restrict__ W2a, const float* __restrict__ W2b,
    h16* __restrict__ Wt1a, h16* __restrict__ Wt1b,
    h16* __restrict__ Wt2a, h16* __restrict__ Wt2b,
    int* __restrict__ deg, float* __restrict__ pooled)
{
    int gtid = blockIdx.x * 256 + threadIdx.x;
    for (int i = gtid; i < N_NODES; i += 416 * 256) deg[i] = 0;
    for (int i = gtid; i < N_GRAPHS * DIM_H; i += 416 * 256) pooled[i] = 0.f;

    int b = blockIdx.x;
    const float* W; h16* Wt; int K, base;
    if (b < 32)       { W = W1a; Wt = Wt1a; K = DIM_IN; base = 0; }
    else if (b < 160) { W = W1b; Wt = Wt1b; K = DIM_H;  base = 32; }
    else if (b < 288) { W = W2a; Wt = Wt2a; K = DIM_H;  base = 160; }
    else              { W = W2b; Wt = Wt2b; K = DIM_H;  base = 288; }
    int t = (b - base) * 256 + threadIdx.x;
    int total = (K >> 3) * DIM_H;
    if (t >= total) return;
    int k8 = t / DIM_H;
    int n  = t - k8 * DIM_H;
    f16x8 o;
#pragma unroll
    for (int j = 0; j < 8; ++j)
        o[j] = (h16)W[(size_t)(k8 * 8 + j) * DIM_H + n];
    *reinterpret_cast<f16x8*>(&Wt[(size_t)n * K + k8 * 8]) = o;
}

// ---------------------------------------------------------------------------
// CSR build: counting sort of edges by dst.  Hierarchical 3-phase scan.
// ---------------------------------------------------------------------------
__global__ __launch_bounds__(256) void k_deg(
    const int* __restrict__ dst, int* __restrict__ deg)
{
    int t = blockIdx.x * 256 + threadIdx.x;
    if (t < N_EDGES) atomicAdd(&deg[dst[t]], 1);
}

__global__ __launch_bounds__(256) void k_scan1(
    const int* __restrict__ deg, int* __restrict__ bsum)
{
    __shared__ int s[256];
    int tid = threadIdx.x;
    int i = blockIdx.x * 256 + tid;
    s[tid] = (i < N_NODES) ? deg[i] : 0;
    __syncthreads();
    for (int off = 128; off > 0; off >>= 1) {
        if (tid < off) s[tid] += s[tid + off];
        __syncthreads();
    }
    if (tid == 0) bsum[blockIdx.x] = s[0];
}

__global__ __launch_bounds__(256) void k_scan2(
    const int* __restrict__ bsum, int* __restrict__ boff)
{
    __shared__ int s[256];
    int tid = threadIdx.x;
    s[tid] = (tid < SCAN_B) ? bsum[tid] : 0;
    __syncthreads();
    for (int off = 1; off < 256; off <<= 1) {
        int u = (tid >= off) ? s[tid - off] : 0;
        __syncthreads();
        s[tid] += u;
        __syncthreads();
    }
    if (tid < SCAN_B) boff[tid] = (tid == 0) ? 0 : s[tid - 1];
}

// phase 3 + csum/csq zeroing (block 0)
__global__ __launch_bounds__(256) void k_scan3(
    const int* __restrict__ deg, const int* __restrict__ boff,
    int* __restrict__ rowptr, int* __restrict__ cursor,
    float* __restrict__ csum)
{
    __shared__ int s[256];
    int tid = threadIdx.x;
    int i = blockIdx.x * 256 + tid;
    int v = (i < N_NODES) ? deg[i] : 0;
    s[tid] = v;
    __syncthreads();
    for (int off = 1; off < 256; off <<= 1) {
        int u = (tid >= off) ? s[tid - off] : 0;
        __syncthreads();
        s[tid] += u;
        __syncthreads();
    }
    int excl = s[tid] - v + boff[blockIdx.x];
    if (i < N_NODES) {
        rowptr[i] = excl;
        cursor[i] = excl;
        if (i == N_NODES - 1) rowptr[N_NODES] = excl + v;   // == N_EDGES
    }
    if (blockIdx.x == 0)
        for (int z = tid; z < 2 * DIM_H; z += 256) csum[z] = 0.f;  // csum+csq
}

__global__ __launch_bounds__(256) void k_fill(
    const int* __restrict__ src, const int* __restrict__ dst,
    int* __restrict__ cursor, int* __restrict__ eidx)
{
    int t = blockIdx.x * 256 + threadIdx.x;
    if (t >= N_EDGES) return;
    int pos = atomicAdd(&cursor[dst[t]], 1);
    eidx[pos] = src[t];
}

// ---------------------------------------------------------------------------
// Gather aggregation: out[v] = X[v] + sum_{u in N_in(v)} X[u]
// ---------------------------------------------------------------------------
__global__ __launch_bounds__(256) void k_gather128(
    const float4* __restrict__ X, const int* __restrict__ rowptr,
    const int* __restrict__ eidx, f16x8* __restrict__ out)
{
    int t = blockIdx.x * 256 + threadIdx.x;
    int v = t >> 4, lane = t & 15;
    if (v >= N_NODES) return;
    int r0 = rowptr[v], r1 = rowptr[v + 1];
    float4 a0 = X[(size_t)v * 32 + lane * 2];
    float4 a1 = X[(size_t)v * 32 + lane * 2 + 1];
    for (int j = r0; j < r1; ++j) {
        int s = eidx[j];
        a0 = add4(a0, X[(size_t)s * 32 + lane * 2]);
        a1 = add4(a1, X[(size_t)s * 32 + lane * 2 + 1]);
    }
    f16x8 o;
    o[0] = (h16)a0.x; o[1] = (h16)a0.y; o[2] = (h16)a0.z; o[3] = (h16)a0.w;
    o[4] = (h16)a1.x; o[5] = (h16)a1.y; o[6] = (h16)a1.z; o[7] = (h16)a1.w;
    out[(size_t)v * 16 + lane] = o;
}

// 512-dim gather + csum/csq re-zero (block 0, for layer-2 stats GEMM).
__global__ __launch_bounds__(256) void k_gather512h(
    const f16x8* __restrict__ X, const int* __restrict__ rowptr,
    const int* __restrict__ eidx, f16x8* __restrict__ out,
    float* __restrict__ csum)
{
    if (blockIdx.x == 0)
        for (int z = threadIdx.x; z < 2 * DIM_H; z += 256) csum[z] = 0.f;

    int t = blockIdx.x * 256 + threadIdx.x;
    int v = t >> 6, lane = t & 63;
    if (v >= N_NODES) return;
    int r0 = rowptr[v], r1 = rowptr[v + 1];
    f16x8 sv = X[(size_t)v * 64 + lane];
    float a[8];
#pragma unroll
    for (int i = 0; i < 8; ++i) a[i] = (float)sv[i];
    int j = r0;
    for (; j + 7 < r1; j += 8) {
        f16x8 b0 = X[(size_t)eidx[j]     * 64 + lane];
        f16x8 b1 = X[(size_t)eidx[j + 1] * 64 + lane];
        f16x8 b2 = X[(size_t)eidx[j + 2] * 64 + lane];
        f16x8 b3 = X[(size_t)eidx[j + 3] * 64 + lane];
        f16x8 b4 = X[(size_t)eidx[j + 4] * 64 + lane];
        f16x8 b5 = X[(size_t)eidx[j + 5] * 64 + lane];
        f16x8 b6 = X[(size_t)eidx[j + 6] * 64 + lane];
        f16x8 b7 = X[(size_t)eidx[j + 7] * 64 + lane];
#pragma unroll
        for (int i = 0; i < 8; ++i)
            a[i] += (((float)b0[i] + (float)b1[i]) + ((float)b2[i] + (float)b3[i]))
                  + (((float)b4[i] + (float)b5[i]) + ((float)b6[i] + (float)b7[i]));
    }
    for (; j + 1 < r1; j += 2) {
        f16x8 b0 = X[(size_t)eidx[j]     * 64 + lane];
        f16x8 b1 = X[(size_t)eidx[j + 1] * 64 + lane];
#pragma unroll
        for (int i = 0; i < 8; ++i) a[i] += (float)b0[i] + (float)b1[i];
    }
    if (j < r1) {
        f16x8 b = X[(size_t)eidx[j] * 64 + lane];
#pragma unroll
        for (int i = 0; i < 8; ++i) a[i] += (float)b[i];
    }
    f16x8 o;
#pragma unroll
    for (int i = 0; i < 8; ++i) o[i] = (h16)a[i];
    out[(size_t)v * 64 + lane] = o;
}

// ---------------------------------------------------------------------------
// MFMA GEMM (fp16 A + fp16 k-major B, fp32 accum, fp16 C):
//   C[M,N] = op(A) @ B + bias
//   AFFINE: in-block BN fold (sf=g*rsqrt(var+eps), cf=be-mu*sf from
//           csum/csq/gam/bet -> LDS), then a -> relu(a*sf[k]+cf[k]) on load.
//   RELU: epilogue relu;  STATS: fused column sum/sum-sq (pre-ReLU)
// BM=128, BN=256, BK=32, single-buffer 24(+4)KB LDS, 2 barriers/K-step,
// register-staged with next-tile prefetch overlapping MFMA (best measured
// of the R15-R18 staging family).
// LDS flat-swizzled (T2): entry(row,kb) at [row*4 + (kb ^ (row&3))]
// -> conflict-free stores, 2-way (free) reads [R14: conflicts ~0].
// 512 threads = 8 waves (2x4), wave tile 64x64, 4x4 frags of 16x16x32.
// Fragment maps (gfx950, learn_hip m89-verified family):
//   A: lane l holds A[l&15][8*(l>>4)+j] ; B: lane l holds B[8*(l>>4)+j][l&15]
//   D: lane l reg r holds D[4*(l>>4)+r][l&15]
// ---------------------------------------------------------------------------
template<bool AFFINE, bool RELU, bool STATS>
__global__ __launch_bounds__(512) void k_gemm_mfma(
    const h16* __restrict__ A, const h16* __restrict__ Bt,
    const float* __restrict__ bias,
    float* __restrict__ csum, float* __restrict__ csq,
    const float* __restrict__ gam, const float* __restrict__ bet,
    h16* __restrict__ C, int M, int N, int K, int lda)
{
    __shared__ f16x8 As[128 * 4];   //  8 KB, swizzled
    __shared__ f16x8 Bs[256 * 4];   // 16 KB
    __shared__ float sfl[DIM_H], cfl[DIM_H];   // 4 KB (AFFINE only)

    const int tid  = threadIdx.x;
    const int lane = tid & 63;
    const int w    = tid >> 6;          // 0..7
    const int wr   = w >> 2;            // 0..1 (row half)
    const int wc   = w & 3;             // 0..3 (col quarter)
    const int l15  = lane & 15;
    const int lk   = lane >> 4;         // k-group 0..3
    const int m0   = blockIdx.x * 128;
    const int n0   = blockIdx.y * 256;

    if (AFFINE) {
        const float invM = 1.0f / (float)N_NODES;
        for (int cc = tid; cc < K; cc += 512) {
            float mu  = csum[cc] * invM;
            float var = csq[cc] * invM - mu * mu;
            float s   = gam[cc] * rsqrtf(var + BN_EPS);
            sfl[cc] = s;
            cfl[cc] = bet[cc] - mu * s;
        }
        __syncthreads();
    }

    // A staging: 1 chunk/thread: row a_row = tid>>2, kb = tid&3
    const int a_row = tid >> 2;         // 0..127
    const int kb    = tid & 3;          // 0..3
    const int aswz  = kb ^ (a_row & 3);
    int ar = m0 + a_row; if (ar >= M) ar = M - 1;     // clamp; stores predicated
    const h16* aptr = A + (size_t)ar * lda + kb * 8;
    // B staging: 2 chunks/thread: cols b_col, b_col+128, same kb
    const int b_col = tid >> 2;         // 0..127  (+128 preserves &3)
    const int bswz  = kb ^ (b_col & 3);
    const h16* bptr = Bt + (size_t)(n0 + b_col) * K + kb * 8;
    const size_t bstride = (size_t)128 * K;   // +128 cols

    f32x4 acc[4][4];
#pragma unroll
    for (int m = 0; m < 4; ++m)
#pragma unroll
        for (int n = 0; n < 4; ++n)
            acc[m][n] = (f32x4){0.f, 0.f, 0.f, 0.f};

    f16x8 av, bw0, bw1;

    auto load_tile = [&](int k0) {
        av  = *reinterpret_cast<const f16x8*>(aptr + k0);
        if (AFFINE) {
            int kk = k0 + kb * 8;
            float4 s0 = *reinterpret_cast<const float4*>(&sfl[kk]);
            float4 s1 = *reinterpret_cast<const float4*>(&sfl[kk + 4]);
            float4 c0 = *reinterpret_cast<const float4*>(&cfl[kk]);
            float4 c1 = *reinterpret_cast<const float4*>(&cfl[kk + 4]);
            float sarr[8] = {s0.x, s0.y, s0.z, s0.w, s1.x, s1.y, s1.z, s1.w};
            float carr[8] = {c0.x, c0.y, c0.z, c0.w, c1.x, c1.y, c1.z, c1.w};
#pragma unroll
            for (int i = 0; i < 8; ++i)
                av[i] = (h16)fmaxf(fmaf((float)av[i], sarr[i], carr[i]), 0.f);
        }
        bw0 = *reinterpret_cast<const f16x8*>(bptr + k0);
        bw1 = *reinterpret_cast<const f16x8*>(bptr + bstride + k0);
    };

    load_tile(0);

    for (int k0 = 0; k0 < K; k0 += 32) {
        __syncthreads();   // previous tile fully consumed
        As[a_row * 4 + aswz]          = av;
        Bs[b_col * 4 + bswz]          = bw0;
        Bs[(b_col + 128) * 4 + bswz]  = bw1;
        __syncthreads();   // tile ready

        if (k0 + 32 < K) load_tile(k0 + 32);   // prefetch overlaps MFMA below

        f16x8 af[4], bf[4];
#pragma unroll
        for (int m = 0; m < 4; ++m) {
            int row = wr * 64 + m * 16 + l15;
            af[m] = As[row * 4 + (lk ^ (row & 3))];
        }
#pragma unroll
        for (int n = 0; n < 4; ++n) {
            int col = wc * 64 + n * 16 + l15;
            bf[n] = Bs[col * 4 + (lk ^ (col & 3))];
        }
#pragma unroll
        for (int m = 0; m < 4; ++m)
#pragma unroll
            for (int n = 0; n < 4; ++n)
                acc[m][n] = __builtin_amdgcn_mfma_f32_16x16x32_f16(
                    af[m], bf[n], acc[m][n], 0, 0, 0);
    }

    // ---- epilogue (fp16 store + optional fused column stats) ----
#pragma unroll
    for (int n = 0; n < 4; ++n) {
        int col = n0 + wc * 64 + n * 16 + l15;
        float bb = bias[col];
        float sp = 0.f, qp = 0.f;
#pragma unroll
        for (int m = 0; m < 4; ++m) {
            int row0 = m0 + wr * 64 + m * 16 + lk * 4;
#pragma unroll
            for (int r = 0; r < 4; ++r) {
                int row = row0 + r;
                if (row < M) {
                    float v = acc[m][n][r] + bb;
                    if (STATS) { sp += v; qp += v * v; }
                    if (RELU) v = fmaxf(v, 0.f);
                    C[(size_t)row * N + col] = (h16)v;
                }
            }
        }
        if (STATS) {
            sp += __shfl_xor(sp, 16); qp += __shfl_xor(qp, 16);
            sp += __shfl_xor(sp, 32); qp += __shfl_xor(qp, 32);
            if (lk == 0) {
                atomicAdd(&csum[col], sp);
                atomicAdd(&csq[col], qp);
            }
        }
    }
}

// ---------------------------------------------------------------------------
// Graph pooling (fp16 H): batch sorted -> local accumulate, boundary atomics
// (391 blocks x 256 threads: wide, latency-hidden; R19's 64-block serial
//  poolhead was 251 us -> reverted)
// ---------------------------------------------------------------------------
__global__ __launch_bounds__(256) void k_pool(
    const h16* __restrict__ H, const int* __restrict__ batch,
    float* __restrict__ pooled)
{
    __shared__ int bg[128];
    int base = blockIdx.x * 128;
    if (threadIdx.x < 128) {
        int r = base + threadIdx.x;
        bg[threadIdx.x] = (r < N_NODES) ? batch[r] : -1;
    }
    __syncthreads();
    int c0 = threadIdx.x;
    float a0 = 0.f, a1 = 0.f;
    int cur = bg[0];
    for (int r = 0; r < 128; ++r) {
        int g = bg[r];
        if (g < 0) break;
        if (g != cur) {
            atomicAdd(&pooled[cur * DIM_H + c0],       a0);
            atomicAdd(&pooled[cur * DIM_H + c0 + 256], a1);
            a0 = a1 = 0.f;
            cur = g;
        }
        size_t row = (size_t)(base + r);
        a0 += (float)H[row * DIM_H + c0];
        a1 += (float)H[row * DIM_H + c0 + 256];
    }
    if (cur >= 0) {
        atomicAdd(&pooled[cur * DIM_H + c0],       a0);
        atomicAdd(&pooled[cur * DIM_H + c0 + 256], a1);
    }
}

// Fused 2-layer head: one block per graph.
//   q = relu(pooled[g] @ Wl1 + bl1);  out[g] = q @ Wl2 + bl2
__global__ __launch_bounds__(512) void k_head(
    const float* __restrict__ pooled,
    const float* __restrict__ Wl1, const float* __restrict__ bl1,
    const float* __restrict__ Wl2, const float* __restrict__ bl2,
    float* __restrict__ out)
{
    __shared__ float rowp[DIM_H];
    __shared__ float qv[DIM_H];
    int g = blockIdx.x, c = threadIdx.x;
    rowp[c] = pooled[(size_t)g * DIM_H + c];
    __syncthreads();
    float acc = 0.f;
    for (int k = 0; k < DIM_H; ++k)
        acc = fmaf(rowp[k], Wl1[(size_t)k * DIM_H + c], acc);
    qv[c] = fmaxf(acc + bl1[c], 0.f);
    __syncthreads();
    if (c < DIM_OUT) {
        float a2 = 0.f;
        for (int k = 0; k < DIM_H; ++k)
            a2 = fmaf(qv[k], Wl2[(size_t)k * DIM_OUT + c], a2);
        out[g * DIM_OUT + c] = a2 + bl2[c];
    }
}

// ---------------------------------------------------------------------------
extern "C" void kernel_launch(void* const* d_in, const int* in_sizes, int n_in,
                              void* d_out, int out_size, void* d_ws, size_t ws_size,
                              hipStream_t stream)
{
    const float* x   = (const float*)d_in[0];
    const int*   ei  = (const int*)d_in[1];
    const int*   src = ei;
    const int*   dst = ei + N_EDGES;
    const int*   batch = (const int*)d_in[2];
    const float* W1a = (const float*)d_in[3];
    const float* b1a = (const float*)d_in[4];
    const float* g1  = (const float*)d_in[5];
    const float* be1 = (const float*)d_in[6];
    const float* W1b = (const float*)d_in[7];
    const float* b1b = (const float*)d_in[8];
    const float* W2a = (const float*)d_in[9];
    const float* b2a = (const float*)d_in[10];
    const float* g2  = (const float*)d_in[11];
    const float* be2 = (const float*)d_in[12];
    const float* W2b = (const float*)d_in[13];
    const float* b2b = (const float*)d_in[14];
    const float* Wl1 = (const float*)d_in[15];
    const float* bl1 = (const float*)d_in[16];
    const float* Wl2 = (const float*)d_in[17];
    const float* bl2 = (const float*)d_in[18];

    char* ws = (char*)d_ws;
    const size_t ROW_H = (size_t)N_NODES * DIM_H * 2;   // 51,200,000

    if (ws_size < 110000000ull) {
        hipMemsetAsync(d_out, 0, (size_t)out_size * 4, stream);
        return;
    }
    h16* B1h = (h16*)(ws + 0);
    h16* B2h = (h16*)(ws + ROW_H);
    h16* XAh = B2h;                                   // 12.8 MB, dead after GEMM1
    char* cp  = ws + 2 * ROW_H;                       // 102,400,000
    int* deg    = (int*)(cp + 0);
    int* rowptr = (int*)(cp + 200192);
    int* cursor = (int*)(cp + 400384);
    int* eidx   = (int*)(cp + 600576);
    char* sm    = cp + 3800576;
    float* csum   = (float*)(sm + 0);                 // [512]
    float* csq    = (float*)(sm + 2048);              // [512], contiguous after csum
    float* pooled = (float*)(sm + 4096);              // [64][512] fp32, 128 KB
    char* wt = sm + 4096 + 131072;
    h16* Wt1a = (h16*)(wt);                           // [512][128] 128 KB
    h16* Wt1b = (h16*)(wt + 131072);                  // [512][512] 512 KB
    h16* Wt2a = (h16*)(wt + 131072 + 524288);
    h16* Wt2b = (h16*)(wt + 131072 + 2 * 524288);
    int* bsum = (int*)(wt + 131072 + 3 * 524288);     // [196]
    int* boff = bsum + 256;                           // [196]

    const dim3 gemm_grid(391, 2);   // ceil(50000/128) x 512/256
    const int EB = (N_EDGES + 255) / 256;

    // 1) weight cast+transpose + deg/pooled zero
    k_wcast_all<<<416, 256, 0, stream>>>(W1a, W1b, W2a, W2b,
                                         Wt1a, Wt1b, Wt2a, Wt2b, deg, pooled);
    // 2-6) CSR build (scan3 zeroes csum/csq for layer-1 stats)
    k_deg<<<EB, 256, 0, stream>>>(dst, deg);
    k_scan1<<<SCAN_B, 256, 0, stream>>>(deg, bsum);
    k_scan2<<<1, 256, 0, stream>>>(bsum, boff);
    k_scan3<<<SCAN_B, 256, 0, stream>>>(deg, boff, rowptr, cursor, csum);
    k_fill<<<EB, 256, 0, stream>>>(src, dst, cursor, eidx);

    // 7-9) layer 1
    k_gather128<<<(N_NODES * 16 + 255) / 256, 256, 0, stream>>>(
        (const float4*)x, rowptr, eidx, (f16x8*)XAh);
    k_gemm_mfma<false, false, true><<<gemm_grid, 512, 0, stream>>>(
        XAh, Wt1a, b1a, csum, csq, nullptr, nullptr, B1h,
        N_NODES, DIM_H, DIM_IN, DIM_IN);
    k_gemm_mfma<true, true, false><<<gemm_grid, 512, 0, stream>>>(
        B1h, Wt1b, b1b, csum, csq, g1, be1, B2h,
        N_NODES, DIM_H, DIM_H, DIM_H);

    // 10-12) layer 2 (gather re-zeroes csum/csq for layer-2 stats)
    k_gather512h<<<(N_NODES * 64) / 256, 256, 0, stream>>>(
        (const f16x8*)B2h, rowptr, eidx, (f16x8*)B1h, csum);
    k_gemm_mfma<false, false, true><<<gemm_grid, 512, 0, stream>>>(
        B1h, Wt2a, b2a, csum, csq, nullptr, nullptr, B2h,
        N_NODES, DIM_H, DIM_H, DIM_H);
    k_gemm_mfma<true, true, false><<<gemm_grid, 512, 0, stream>>>(
        B2h, Wt2b, b2b, csum, csq, g2, be2, B1h,
        N_NODES, DIM_H, DIM_H, DIM_H);

    // 13-14) pool (wide, atomic) + fused head
    k_pool<<<(N_NODES + 127) / 128, 256, 0, stream>>>(B1h, batch, pooled);
    k_head<<<N_GRAPHS, 512, 0, stream>>>(pooled, Wl1, bl1, Wl2, bl2,
                                         (float*)d_out);
}